// Round 3
// baseline (417.855 us; speedup 1.0000x reference)
//
#include <hip/hip_runtime.h>
#include <hip/hip_bf16.h>

typedef __attribute__((ext_vector_type(8))) short short8;
typedef __attribute__((ext_vector_type(4))) float f32x4;
typedef unsigned short u16;

#define NEGINF (-1e9f)

__device__ __forceinline__ u16 f2bf(float x) {
    union { float f; unsigned int u; } v; v.f = x;
    unsigned int r = v.u + 0x7fff + ((v.u >> 16) & 1);
    return (u16)(r >> 16);
}

__device__ __forceinline__ void gload16(const void* g, void* l) {
    __builtin_amdgcn_global_load_lds(
        (const __attribute__((address_space(1))) unsigned int*)g,
        (__attribute__((address_space(3))) unsigned int*)l, 16, 0, 0);
}

// ---------------- cast hidden fp32 -> bf16 ----------------
__global__ __launch_bounds__(256) void cast_hidden_kernel(const float* __restrict__ in,
                                                          u16* __restrict__ out) {
    int idx = (blockIdx.x * 256 + threadIdx.x) * 4;
    float4 v = *(const float4*)&in[idx];
    ushort4 o;
    o.x = f2bf(v.x); o.y = f2bf(v.y); o.z = f2bf(v.z); o.w = f2bf(v.w);
    *(ushort4*)&out[idx] = o;
}

// ---------------- weight prep: w = pw * (rm^T sm) + (r^T s), bf16 out ----------------
__global__ __launch_bounds__(256) void prep_w_kernel(const float* __restrict__ w,
                                                     const float* __restrict__ rm,
                                                     const float* __restrict__ sm,
                                                     const float* __restrict__ ra,
                                                     const float* __restrict__ sa,
                                                     const int* __restrict__ lang,
                                                     u16* __restrict__ out, int rows) {
    const int li = lang[0];
    int idx = blockIdx.x * 256 + threadIdx.x;
    int e = idx >> 8;
    int f = (idx & 255) * 4;
    float4 pw = *(const float4*)&w[(size_t)e * 1024 + f];
    float mul0 = 0.f, mul1 = 0.f, mul2 = 0.f, mul3 = 0.f;
    float add0 = 0.f, add1 = 0.f, add2 = 0.f, add3 = 0.f;
#pragma unroll
    for (int r = 0; r < 4; r++) {
        float a = rm[(size_t)(li * 4 + r) * rows + e];
        float4 b = *(const float4*)&sm[(size_t)(li * 4 + r) * 1024 + f];
        float c = ra[(size_t)(li * 4 + r) * rows + e];
        float4 d = *(const float4*)&sa[(size_t)(li * 4 + r) * 1024 + f];
        mul0 += a * b.x; mul1 += a * b.y; mul2 += a * b.z; mul3 += a * b.w;
        add0 += c * d.x; add1 += c * d.y; add2 += c * d.z; add3 += c * d.w;
    }
    ushort4 o;
    o.x = f2bf(pw.x * mul0 + add0);
    o.y = f2bf(pw.y * mul1 + add1);
    o.z = f2bf(pw.z * mul2 + add2);
    o.w = f2bf(pw.w * mul3 + add3);
    *(ushort4*)&out[(size_t)e * 1024 + f] = o;
}

// ---------------- 128x128 bf16 MFMA GEMM, A:MxK row-major, W:NxK row-major ----------------
// EPI 0: qkv epilogue (scatter q/k/vt).  EPI 1: fp32 out + bias.
template <int EPI>
__global__ __launch_bounds__(256) void gemm_bf16(const u16* __restrict__ A,
                                                 const u16* __restrict__ W,
                                                 const float* __restrict__ bias,
                                                 int K,
                                                 float* __restrict__ outF,
                                                 u16* __restrict__ qb,
                                                 u16* __restrict__ kb,
                                                 u16* __restrict__ vtb) {
    __shared__ __align__(16) u16 As[128 * 32];
    __shared__ __align__(16) u16 Bs[128 * 32];
    const int t = threadIdx.x;
    const int lane = t & 63, wv = t >> 6;
    const int lr = lane & 15, lk = lane >> 4;
    const int wr = wv >> 1, wc = wv & 1;
    const int m0 = blockIdx.y * 128, n0 = blockIdx.x * 128;

    const int rowS = t >> 2, kcS = t & 3;
    const u16* gA0 = A + (size_t)(m0 + rowS) * K + kcS * 8;
    const u16* gA1 = gA0 + (size_t)64 * K;
    const u16* gB0 = W + (size_t)(n0 + rowS) * K + kcS * 8;
    const u16* gB1 = gB0 + (size_t)64 * K;
    char* ldsA0 = (char*)As + wv * 1024;
    char* ldsA1 = (char*)As + 4096 + wv * 1024;
    char* ldsB0 = (char*)Bs + wv * 1024;
    char* ldsB1 = (char*)Bs + 4096 + wv * 1024;

    f32x4 acc[4][4] = {};

    for (int k0 = 0; k0 < K; k0 += 32) {
        gload16(gA0 + k0, ldsA0);
        gload16(gA1 + k0, ldsA1);
        gload16(gB0 + k0, ldsB0);
        gload16(gB1 + k0, ldsB1);
        __syncthreads();
        short8 af[4], bf[4];
#pragma unroll
        for (int mi = 0; mi < 4; mi++)
            af[mi] = *(const short8*)&As[(wr * 64 + mi * 16 + lr) * 32 + lk * 8];
#pragma unroll
        for (int ni = 0; ni < 4; ni++)
            bf[ni] = *(const short8*)&Bs[(wc * 64 + ni * 16 + lr) * 32 + lk * 8];
#pragma unroll
        for (int mi = 0; mi < 4; mi++)
#pragma unroll
            for (int ni = 0; ni < 4; ni++)
                acc[mi][ni] = __builtin_amdgcn_mfma_f32_16x16x32_bf16(af[mi], bf[ni], acc[mi][ni], 0, 0, 0);
        __syncthreads();
    }

#pragma unroll
    for (int mi = 0; mi < 4; mi++) {
#pragma unroll
        for (int ni = 0; ni < 4; ni++) {
            int n = n0 + wc * 64 + ni * 16 + lr;
            float bv = bias[n];
#pragma unroll
            for (int i = 0; i < 4; i++) {
                int m = m0 + wr * 64 + mi * 16 + lk * 4 + i;
                float val = acc[mi][ni][i] + bv;
                if (EPI == 0) {
                    int tt = m >> 1, bb = m & 1;
                    int h = n / 192;
                    int rem = n - h * 192;
                    int s = rem >> 6, d = rem & 63;
                    size_t bh = (size_t)(bb * 16 + h);
                    if (s == 0)      qb[(bh * 2048 + tt) * 64 + d] = f2bf(val * 0.125f);
                    else if (s == 1) kb[(bh * 2048 + tt) * 64 + d] = f2bf(val);
                    else             vtb[(bh * 64 + d) * 2048 + tt] = f2bf(val);
                } else {
                    outF[(size_t)m * 1024 + n] = val;
                }
            }
        }
    }
}

// ---------------- causal flash attention ----------------
// q: (BH, T, 64) bf16 scaled; k: (BH, T, 64) bf16; vt: (BH, 64, T) bf16
// ctx out: (T*B, 1024) bf16
__global__ __launch_bounds__(256) void attn_kernel(const u16* __restrict__ qb,
                                                   const u16* __restrict__ kb,
                                                   const u16* __restrict__ vtb,
                                                   u16* __restrict__ ctx) {
    __shared__ __align__(16) u16 Plds[4][16][72];
    const int lane = threadIdx.x & 63, wv = threadIdx.x >> 6;
    const int lr = lane & 15, lk = lane >> 4;
    const int bh = blockIdx.y;
    const int q0 = blockIdx.x * 64 + wv * 16;
    const u16* Qp = qb + ((size_t)bh * 2048 + q0) * 64;
    const u16* Kp = kb + (size_t)bh * 2048 * 64;
    const u16* Vp = vtb + (size_t)bh * 64 * 2048;

    short8 qf0 = *(const short8*)&Qp[lr * 64 + lk * 8];
    short8 qf1 = *(const short8*)&Qp[lr * 64 + 32 + lk * 8];

    f32x4 acc[4] = {};
    float mrow[4], ssum[4];
#pragma unroll
    for (int i = 0; i < 4; i++) { mrow[i] = -3e38f; ssum[i] = 0.f; }

    for (int kv0 = 0; kv0 < q0 + 16; kv0 += 64) {
        f32x4 sb[4];
#pragma unroll
        for (int nj = 0; nj < 4; nj++) {
            const u16* kr = Kp + (size_t)(kv0 + nj * 16 + lr) * 64 + lk * 8;
            short8 kf0 = *(const short8*)kr;
            short8 kf1 = *(const short8*)(kr + 32);
            f32x4 z = {0.f, 0.f, 0.f, 0.f};
            z = __builtin_amdgcn_mfma_f32_16x16x32_bf16(qf0, kf0, z, 0, 0, 0);
            z = __builtin_amdgcn_mfma_f32_16x16x32_bf16(qf1, kf1, z, 0, 0, 0);
            sb[nj] = z;
        }
        if (kv0 + 63 > q0) {
#pragma unroll
            for (int nj = 0; nj < 4; nj++) {
                int kv = kv0 + nj * 16 + lr;
#pragma unroll
                for (int i = 0; i < 4; i++) {
                    int qr = q0 + lk * 4 + i;
                    if (kv > qr) sb[nj][i] = NEGINF;
                }
            }
        }
        float scale[4];
#pragma unroll
        for (int i = 0; i < 4; i++) {
            float mx = fmaxf(fmaxf(sb[0][i], sb[1][i]), fmaxf(sb[2][i], sb[3][i]));
            mx = fmaxf(mx, __shfl_xor(mx, 1, 16));
            mx = fmaxf(mx, __shfl_xor(mx, 2, 16));
            mx = fmaxf(mx, __shfl_xor(mx, 4, 16));
            mx = fmaxf(mx, __shfl_xor(mx, 8, 16));
            float mnew = fmaxf(mrow[i], mx);
            scale[i] = __expf(mrow[i] - mnew);
            mrow[i] = mnew;
            float psum = 0.f;
#pragma unroll
            for (int nj = 0; nj < 4; nj++) {
                float p = __expf(sb[nj][i] - mnew);
                sb[nj][i] = p;
                psum += p;
            }
            psum += __shfl_xor(psum, 1, 16);
            psum += __shfl_xor(psum, 2, 16);
            psum += __shfl_xor(psum, 4, 16);
            psum += __shfl_xor(psum, 8, 16);
            ssum[i] = ssum[i] * scale[i] + psum;
        }
#pragma unroll
        for (int nj = 0; nj < 4; nj++)
#pragma unroll
            for (int i = 0; i < 4; i++)
                Plds[wv][lk * 4 + i][nj * 16 + lr] = f2bf(sb[nj][i]);
#pragma unroll
        for (int ni = 0; ni < 4; ni++)
#pragma unroll
            for (int i = 0; i < 4; i++)
                acc[ni][i] *= scale[i];
        short8 pf0 = *(const short8*)&Plds[wv][lr][lk * 8];
        short8 pf1 = *(const short8*)&Plds[wv][lr][32 + lk * 8];
#pragma unroll
        for (int ni = 0; ni < 4; ni++) {
            const u16* vr = Vp + (size_t)(ni * 16 + lr) * 2048 + kv0 + lk * 8;
            short8 vf0 = *(const short8*)vr;
            short8 vf1 = *(const short8*)(vr + 32);
            acc[ni] = __builtin_amdgcn_mfma_f32_16x16x32_bf16(pf0, vf0, acc[ni], 0, 0, 0);
            acc[ni] = __builtin_amdgcn_mfma_f32_16x16x32_bf16(pf1, vf1, acc[ni], 0, 0, 0);
        }
    }

    int bb = bh >> 4, h = bh & 15;
#pragma unroll
    for (int ni = 0; ni < 4; ni++) {
#pragma unroll
        for (int i = 0; i < 4; i++) {
            int tq = q0 + lk * 4 + i;
            float val = acc[ni][i] / ssum[i];
            ctx[(size_t)(tq * 2 + bb) * 1024 + h * 64 + ni * 16 + lr] = f2bf(val);
        }
    }
}

extern "C" void kernel_launch(void* const* d_in, const int* in_sizes, int n_in,
                              void* d_out, int out_size, void* d_ws, size_t ws_size,
                              hipStream_t stream) {
    const float* hs     = (const float*)d_in[0];
    const float* proj_w = (const float*)d_in[1];
    const float* proj_b = (const float*)d_in[2];
    const float* out_w  = (const float*)d_in[3];
    const float* out_b  = (const float*)d_in[4];
    const float* rm_i   = (const float*)d_in[5];
    const float* sm_i   = (const float*)d_in[6];
    const float* rm_o   = (const float*)d_in[7];
    const float* sm_o   = (const float*)d_in[8];
    const float* r_i    = (const float*)d_in[9];
    const float* s_i    = (const float*)d_in[10];
    const float* r_o    = (const float*)d_in[11];
    const float* s_o    = (const float*)d_in[12];
    const int*   lang   = (const int*)d_in[13];
    float* out = (float*)d_out;

    char* ws = (char*)d_ws;
    u16* hsb   = (u16*)(ws);
    u16* w_in  = (u16*)(ws + (size_t)(8 << 20));
    u16* w_out = (u16*)(ws + (size_t)(14 << 20));
    u16* qb    = (u16*)(ws + (size_t)(16 << 20));
    u16* kb    = (u16*)(ws + (size_t)(24 << 20));
    u16* vtb   = (u16*)(ws + (size_t)(32 << 20));
    u16* ctxb  = (u16*)(ws + (size_t)(40 << 20));

    cast_hidden_kernel<<<dim3(4096), dim3(256), 0, stream>>>(hs, hsb);
    prep_w_kernel<<<dim3(3072), dim3(256), 0, stream>>>(proj_w, rm_i, sm_i, r_i, s_i, lang, w_in, 3072);
    prep_w_kernel<<<dim3(1024), dim3(256), 0, stream>>>(out_w, rm_o, sm_o, r_o, s_o, lang, w_out, 1024);
    gemm_bf16<0><<<dim3(24, 32), dim3(256), 0, stream>>>(hsb, w_in, proj_b, 1024, (float*)nullptr, qb, kb, vtb);
    attn_kernel<<<dim3(32, 32), dim3(256), 0, stream>>>(qb, kb, vtb, ctxb);
    gemm_bf16<1><<<dim3(8, 32), dim3(256), 0, stream>>>(ctxb, w_out, out_b, 1024, out, (u16*)nullptr, (u16*)nullptr, (u16*)nullptr);
}

// Round 6
// 250.108 us; speedup vs baseline: 1.6707x; 1.6707x over previous
//
#include <hip/hip_runtime.h>
#include <hip/hip_bf16.h>

typedef __attribute__((ext_vector_type(8))) short short8;
typedef __attribute__((ext_vector_type(4))) float f32x4;
typedef unsigned short u16;

#define NEGINF (-1e9f)

__device__ __forceinline__ u16 f2bf(float x) {
    union { float f; unsigned int u; } v; v.f = x;
    unsigned int r = v.u + 0x7fff + ((v.u >> 16) & 1);
    return (u16)(r >> 16);
}

__device__ __forceinline__ void gload16(const void* g, void* l) {
    __builtin_amdgcn_global_load_lds(
        (const __attribute__((address_space(1))) unsigned int*)g,
        (__attribute__((address_space(3))) unsigned int*)l, 16, 0, 0);
}

// ---------------- cast hidden fp32 -> bf16 ----------------
__global__ __launch_bounds__(256) void cast_hidden_kernel(const float* __restrict__ in,
                                                          u16* __restrict__ out) {
    int idx = (blockIdx.x * 256 + threadIdx.x) * 4;
    float4 v = *(const float4*)&in[idx];
    ushort4 o;
    o.x = f2bf(v.x); o.y = f2bf(v.y); o.z = f2bf(v.z); o.w = f2bf(v.w);
    *(ushort4*)&out[idx] = o;
}

// ---------------- weight prep: w = pw * (rm^T sm) + (r^T s), bf16 out ----------------
__global__ __launch_bounds__(256) void prep_w_kernel(const float* __restrict__ w,
                                                     const float* __restrict__ rm,
                                                     const float* __restrict__ sm,
                                                     const float* __restrict__ ra,
                                                     const float* __restrict__ sa,
                                                     const int* __restrict__ lang,
                                                     u16* __restrict__ out, int rows) {
    const int li = lang[0];
    int idx = blockIdx.x * 256 + threadIdx.x;
    int e = idx >> 8;
    int f = (idx & 255) * 4;
    float4 pw = *(const float4*)&w[(size_t)e * 1024 + f];
    float mul0 = 0.f, mul1 = 0.f, mul2 = 0.f, mul3 = 0.f;
    float add0 = 0.f, add1 = 0.f, add2 = 0.f, add3 = 0.f;
#pragma unroll
    for (int r = 0; r < 4; r++) {
        float a = rm[(size_t)(li * 4 + r) * rows + e];
        float4 b = *(const float4*)&sm[(size_t)(li * 4 + r) * 1024 + f];
        float c = ra[(size_t)(li * 4 + r) * rows + e];
        float4 d = *(const float4*)&sa[(size_t)(li * 4 + r) * 1024 + f];
        mul0 += a * b.x; mul1 += a * b.y; mul2 += a * b.z; mul3 += a * b.w;
        add0 += c * d.x; add1 += c * d.y; add2 += c * d.z; add3 += c * d.w;
    }
    ushort4 o;
    o.x = f2bf(pw.x * mul0 + add0);
    o.y = f2bf(pw.y * mul1 + add1);
    o.z = f2bf(pw.z * mul2 + add2);
    o.w = f2bf(pw.w * mul3 + add3);
    *(ushort4*)&out[(size_t)e * 1024 + f] = o;
}

// ---------------- 128x128 bf16 MFMA GEMM, A:MxK row-major, W:NxK row-major ----------------
// EPI 0: qkv epilogue (scatter q/k/vt).  EPI 1: fp32 out + bias.
template <int EPI>
__global__ __launch_bounds__(256) void gemm_bf16(const u16* __restrict__ A,
                                                 const u16* __restrict__ W,
                                                 const float* __restrict__ bias,
                                                 int K,
                                                 float* __restrict__ outF,
                                                 u16* __restrict__ qb,
                                                 u16* __restrict__ kb,
                                                 u16* __restrict__ vtb) {
    __shared__ __align__(16) u16 As[128 * 32];
    __shared__ __align__(16) u16 Bs[128 * 32];
    const int t = threadIdx.x;
    const int lane = t & 63, wv = t >> 6;
    const int lr = lane & 15, lk = lane >> 4;
    const int wr = wv >> 1, wc = wv & 1;
    const int m0 = blockIdx.y * 128, n0 = blockIdx.x * 128;

    const int rowS = t >> 2, kcS = t & 3;
    const u16* gA0 = A + (size_t)(m0 + rowS) * K + kcS * 8;
    const u16* gA1 = gA0 + (size_t)64 * K;
    const u16* gB0 = W + (size_t)(n0 + rowS) * K + kcS * 8;
    const u16* gB1 = gB0 + (size_t)64 * K;
    char* ldsA0 = (char*)As + wv * 1024;
    char* ldsA1 = (char*)As + 4096 + wv * 1024;
    char* ldsB0 = (char*)Bs + wv * 1024;
    char* ldsB1 = (char*)Bs + 4096 + wv * 1024;

    f32x4 acc[4][4] = {};

    for (int k0 = 0; k0 < K; k0 += 32) {
        gload16(gA0 + k0, ldsA0);
        gload16(gA1 + k0, ldsA1);
        gload16(gB0 + k0, ldsB0);
        gload16(gB1 + k0, ldsB1);
        __syncthreads();
        short8 af[4], bf[4];
#pragma unroll
        for (int mi = 0; mi < 4; mi++)
            af[mi] = *(const short8*)&As[(wr * 64 + mi * 16 + lr) * 32 + lk * 8];
#pragma unroll
        for (int ni = 0; ni < 4; ni++)
            bf[ni] = *(const short8*)&Bs[(wc * 64 + ni * 16 + lr) * 32 + lk * 8];
#pragma unroll
        for (int mi = 0; mi < 4; mi++)
#pragma unroll
            for (int ni = 0; ni < 4; ni++)
                acc[mi][ni] = __builtin_amdgcn_mfma_f32_16x16x32_bf16(af[mi], bf[ni], acc[mi][ni], 0, 0, 0);
        __syncthreads();
    }

#pragma unroll
    for (int mi = 0; mi < 4; mi++) {
#pragma unroll
        for (int ni = 0; ni < 4; ni++) {
            int n = n0 + wc * 64 + ni * 16 + lr;
            float bv = bias[n];
#pragma unroll
            for (int i = 0; i < 4; i++) {
                int m = m0 + wr * 64 + mi * 16 + lk * 4 + i;
                float val = acc[mi][ni][i] + bv;
                if (EPI == 0) {
                    int tt = m >> 1, bb = m & 1;
                    int h = n / 192;
                    int rem = n - h * 192;
                    int s = rem >> 6, d = rem & 63;
                    size_t bh = (size_t)(bb * 16 + h);
                    if (s == 0)      qb[(bh * 2048 + tt) * 64 + d] = f2bf(val * 0.125f);
                    else if (s == 1) kb[(bh * 2048 + tt) * 64 + d] = f2bf(val);
                    else             vtb[(bh * 64 + d) * 2048 + tt] = f2bf(val);
                } else {
                    outF[(size_t)m * 1024 + n] = val;
                }
            }
        }
    }
}

// ---------------- causal flash attention (LDS-staged, paired strips) ----------------
// q: (BH, T, 64) bf16 scaled; k: (BH, T, 64) bf16; vt: (BH, 64, T) bf16
// ctx out: (T*B, 1024) bf16
// Grid: 512 blocks linear. Block handles strips {pair, 31-pair} of 64 q-rows each.
__global__ __launch_bounds__(256) void attn_kernel(const u16* __restrict__ qb,
                                                   const u16* __restrict__ kb,
                                                   const u16* __restrict__ vtb,
                                                   u16* __restrict__ ctx) {
    // K tile: [64 kv][64 d] bf16, 8 chunks of 16B per row, chunk swizzled by c^(r&7).
    // V tile: [64 d][64 kv] bf16 (from vtb), same swizzle.
    __shared__ __align__(16) u16 Ks[2][4096];
    __shared__ __align__(16) u16 Vs[2][4096];
    __shared__ __align__(16) u16 Plds[4][16][72];

    const int t = threadIdx.x;
    const int lane = t & 63, wv = t >> 6;
    const int lr = lane & 15, lk = lane >> 4;

    // XCD-chunked mapping: blocks with the same bh land on the same XCD (d%8).
    const int d = blockIdx.x;
    const int bh = (d & 7) * 4 + ((d >> 3) >> 4);
    const int pair = (d >> 3) & 15;

    const u16* Kg = kb + (size_t)bh * 2048 * 64;
    const u16* Vg = vtb + (size_t)bh * 64 * 2048;
    const int bb = bh >> 4, h = bh & 15;

    // staging indices (per thread, two passes of 256 chunks)
    // chunk p -> row r=p>>3, phys col cph=p&7, source col csrc=cph^(r&7)
    const int p0 = wv * 64 + lane;      // pass 0 chunk
    const int r0 = p0 >> 3, c0 = (p0 & 7) ^ (r0 & 7);
    const int p1 = 256 + p0;            // pass 1 chunk
    const int r1 = p1 >> 3, c1 = (p1 & 7) ^ (r1 & 7);
    const int ldsOff0 = (wv * 64) * 8;          // u16 offset of wave-uniform base, pass 0
    const int ldsOff1 = (256 + wv * 64) * 8;    // pass 1

#pragma unroll 1
    for (int sidx = 0; sidx < 2; sidx++) {
        const int strip = sidx == 0 ? pair : 31 - pair;
        const int q0 = strip * 64 + wv * 16;
        const u16* Qp = qb + ((size_t)bh * 2048 + q0) * 64;
        short8 qf0 = *(const short8*)&Qp[lr * 64 + lk * 8];
        short8 qf1 = *(const short8*)&Qp[lr * 64 + 32 + lk * 8];

        f32x4 acc[4] = {};
        float mrow[4], ssum[4];
#pragma unroll
        for (int i = 0; i < 4; i++) { mrow[i] = -3e38f; ssum[i] = 0.f; }

        const int nt = strip + 1;
        int buf = 0;

        // prologue: stage tile 0
        {
            gload16(Kg + (size_t)(0 + r0) * 64 + c0 * 8, &Ks[0][ldsOff0]);
            gload16(Kg + (size_t)(0 + r1) * 64 + c1 * 8, &Ks[0][ldsOff1]);
            gload16(Vg + (size_t)r0 * 2048 + 0 + c0 * 8, &Vs[0][ldsOff0]);
            gload16(Vg + (size_t)r1 * 2048 + 0 + c1 * 8, &Vs[0][ldsOff1]);
        }
        asm volatile("s_waitcnt vmcnt(0)" ::: "memory");
        __syncthreads();

#pragma unroll 1
        for (int tt = 0; tt < nt; tt++) {
            const int kv0 = tt * 64;
            // issue next-tile stage before compute (T3-lite)
            if (tt + 1 < nt) {
                const int nkv = kv0 + 64;
                gload16(Kg + (size_t)(nkv + r0) * 64 + c0 * 8, &Ks[buf ^ 1][ldsOff0]);
                gload16(Kg + (size_t)(nkv + r1) * 64 + c1 * 8, &Ks[buf ^ 1][ldsOff1]);
                gload16(Vg + (size_t)r0 * 2048 + nkv + c0 * 8, &Vs[buf ^ 1][ldsOff0]);
                gload16(Vg + (size_t)r1 * 2048 + nkv + c1 * 8, &Vs[buf ^ 1][ldsOff1]);
            }

            // ---- QK^T ----
            f32x4 sb[4];
#pragma unroll
            for (int nj = 0; nj < 4; nj++) {
                const int r = nj * 16 + lr;
                short8 kf0 = *(const short8*)&Ks[buf][r * 64 + ((lk    ) ^ (r & 7)) * 8];
                short8 kf1 = *(const short8*)&Ks[buf][r * 64 + ((lk + 4) ^ (r & 7)) * 8];
                f32x4 z = {0.f, 0.f, 0.f, 0.f};
                z = __builtin_amdgcn_mfma_f32_16x16x32_bf16(qf0, kf0, z, 0, 0, 0);
                z = __builtin_amdgcn_mfma_f32_16x16x32_bf16(qf1, kf1, z, 0, 0, 0);
                sb[nj] = z;
            }
            if (kv0 + 63 > q0) {
#pragma unroll
                for (int nj = 0; nj < 4; nj++) {
                    int kv = kv0 + nj * 16 + lr;
#pragma unroll
                    for (int i = 0; i < 4; i++) {
                        int qr = q0 + lk * 4 + i;
                        if (kv > qr) sb[nj][i] = NEGINF;
                    }
                }
            }
            // ---- online softmax ----
            float scale[4];
#pragma unroll
            for (int i = 0; i < 4; i++) {
                float mx = fmaxf(fmaxf(sb[0][i], sb[1][i]), fmaxf(sb[2][i], sb[3][i]));
                mx = fmaxf(mx, __shfl_xor(mx, 1, 16));
                mx = fmaxf(mx, __shfl_xor(mx, 2, 16));
                mx = fmaxf(mx, __shfl_xor(mx, 4, 16));
                mx = fmaxf(mx, __shfl_xor(mx, 8, 16));
                float mnew = fmaxf(mrow[i], mx);
                scale[i] = __expf(mrow[i] - mnew);
                mrow[i] = mnew;
                float psum = 0.f;
#pragma unroll
                for (int nj = 0; nj < 4; nj++) {
                    float p = __expf(sb[nj][i] - mnew);
                    sb[nj][i] = p;
                    psum += p;
                }
                psum += __shfl_xor(psum, 1, 16);
                psum += __shfl_xor(psum, 2, 16);
                psum += __shfl_xor(psum, 4, 16);
                psum += __shfl_xor(psum, 8, 16);
                ssum[i] = ssum[i] * scale[i] + psum;
            }
#pragma unroll
            for (int nj = 0; nj < 4; nj++)
#pragma unroll
                for (int i = 0; i < 4; i++)
                    Plds[wv][lk * 4 + i][nj * 16 + lr] = f2bf(sb[nj][i]);
#pragma unroll
            for (int ni = 0; ni < 4; ni++)
#pragma unroll
                for (int i = 0; i < 4; i++)
                    acc[ni][i] *= scale[i];
            short8 pf0 = *(const short8*)&Plds[wv][lr][lk * 8];
            short8 pf1 = *(const short8*)&Plds[wv][lr][32 + lk * 8];
            // ---- PV ----
#pragma unroll
            for (int ni = 0; ni < 4; ni++) {
                const int r = ni * 16 + lr;
                short8 vf0 = *(const short8*)&Vs[buf][r * 64 + ((lk    ) ^ (r & 7)) * 8];
                short8 vf1 = *(const short8*)&Vs[buf][r * 64 + ((lk + 4) ^ (r & 7)) * 8];
                acc[ni] = __builtin_amdgcn_mfma_f32_16x16x32_bf16(pf0, vf0, acc[ni], 0, 0, 0);
                acc[ni] = __builtin_amdgcn_mfma_f32_16x16x32_bf16(pf1, vf1, acc[ni], 0, 0, 0);
            }

            asm volatile("s_waitcnt vmcnt(0)" ::: "memory");
            __syncthreads();
            buf ^= 1;
        }

#pragma unroll
        for (int ni = 0; ni < 4; ni++) {
#pragma unroll
            for (int i = 0; i < 4; i++) {
                int tq = q0 + lk * 4 + i;
                float val = acc[ni][i] / ssum[i];
                ctx[(size_t)(tq * 2 + bb) * 1024 + h * 64 + ni * 16 + lr] = f2bf(val);
            }
        }
        __syncthreads();
    }
}

extern "C" void kernel_launch(void* const* d_in, const int* in_sizes, int n_in,
                              void* d_out, int out_size, void* d_ws, size_t ws_size,
                              hipStream_t stream) {
    const float* hs     = (const float*)d_in[0];
    const float* proj_w = (const float*)d_in[1];
    const float* proj_b = (const float*)d_in[2];
    const float* out_w  = (const float*)d_in[3];
    const float* out_b  = (const float*)d_in[4];
    const float* rm_i   = (const float*)d_in[5];
    const float* sm_i   = (const float*)d_in[6];
    const float* rm_o   = (const float*)d_in[7];
    const float* sm_o   = (const float*)d_in[8];
    const float* r_i    = (const float*)d_in[9];
    const float* s_i    = (const float*)d_in[10];
    const float* r_o    = (const float*)d_in[11];
    const float* s_o    = (const float*)d_in[12];
    const int*   lang   = (const int*)d_in[13];
    float* out = (float*)d_out;

    char* ws = (char*)d_ws;
    u16* hsb   = (u16*)(ws);
    u16* w_in  = (u16*)(ws + (size_t)(8 << 20));
    u16* w_out = (u16*)(ws + (size_t)(14 << 20));
    u16* qb    = (u16*)(ws + (size_t)(16 << 20));
    u16* kb    = (u16*)(ws + (size_t)(24 << 20));
    u16* vtb   = (u16*)(ws + (size_t)(32 << 20));
    u16* ctxb  = (u16*)(ws + (size_t)(40 << 20));

    cast_hidden_kernel<<<dim3(4096), dim3(256), 0, stream>>>(hs, hsb);
    prep_w_kernel<<<dim3(3072), dim3(256), 0, stream>>>(proj_w, rm_i, sm_i, r_i, s_i, lang, w_in, 3072);
    prep_w_kernel<<<dim3(1024), dim3(256), 0, stream>>>(out_w, rm_o, sm_o, r_o, s_o, lang, w_out, 1024);
    gemm_bf16<0><<<dim3(24, 32), dim3(256), 0, stream>>>(hsb, w_in, proj_b, 1024, (float*)nullptr, qb, kb, vtb);
    attn_kernel<<<dim3(512), dim3(256), 0, stream>>>(qb, kb, vtb, ctxb);
    gemm_bf16<1><<<dim3(8, 32), dim3(256), 0, stream>>>(ctxb, w_out, out_b, 1024, out, (u16*)nullptr, (u16*)nullptr, (u16*)nullptr);
}